// Round 9
// baseline (254.493 us; speedup 1.0000x reference)
//
#include <hip/hip_runtime.h>

#define NN 50000
#define EE 800000
#define NB ((NN + 1023) / 1024)   // 49 scan blocks
#define DEGB ((EE + 255) / 256)   // 3125 deg-count blocks
#define NCH 8
#define CHW 32

typedef _Float16 half8v __attribute__((ext_vector_type(8)));
typedef _Float16 half4v __attribute__((ext_vector_type(4)));
typedef float f32x4 __attribute__((ext_vector_type(4)));

// ---------------- MFMA fp16 GEMM, double-buffered; blocked output [8][NN][32] ----------------
__global__ __launch_bounds__(256) void gemm1_mfma(const float* __restrict__ A,
                                                  const _Float16* __restrict__ BT,
                                                  const float* __restrict__ dinv,
                                                  _Float16* __restrict__ C, int M) {
    __shared__ _Float16 Ah[2][64][40];
    __shared__ _Float16 Bh[2][128][40];
    int tid = threadIdx.x;
    int bm = blockIdx.y * 64, bn = blockIdx.x * 128;
    int w = tid >> 6, l = tid & 63;
    int wr = w >> 1, wc = w & 1;
    int lr = l & 15, lg = l >> 4;
    int ar0 = tid >> 3, ac0 = tid & 7;
    int ar1 = (tid + 256) >> 3, ac1 = (tid + 256) & 7;
    int bn0 = tid >> 2, bk0 = tid & 3;
    int bn1 = (tid + 256) >> 2, bk1 = (tid + 256) & 3;
    f32x4 acc[2][4] = {};
    float4 aR0, aR1;
    half8v bR0, bR1;

    auto load_regs = [&](int k0) {
        int gm0 = bm + ar0, gm1 = bm + ar1;
        aR0 = (gm0 < M) ? *(const float4*)&A[(size_t)gm0 * 256 + k0 + ac0 * 4]
                        : make_float4(0.f, 0.f, 0.f, 0.f);
        aR1 = (gm1 < M) ? *(const float4*)&A[(size_t)gm1 * 256 + k0 + ac1 * 4]
                        : make_float4(0.f, 0.f, 0.f, 0.f);
        bR0 = *(const half8v*)&BT[(size_t)(bn + bn0) * 256 + k0 + bk0 * 8];
        bR1 = *(const half8v*)&BT[(size_t)(bn + bn1) * 256 + k0 + bk1 * 8];
    };
    auto store_lds = [&](int buf) {
        half4v h0, h1;
        h0[0] = (_Float16)aR0.x; h0[1] = (_Float16)aR0.y;
        h0[2] = (_Float16)aR0.z; h0[3] = (_Float16)aR0.w;
        h1[0] = (_Float16)aR1.x; h1[1] = (_Float16)aR1.y;
        h1[2] = (_Float16)aR1.z; h1[3] = (_Float16)aR1.w;
        *(half4v*)&Ah[buf][ar0][ac0 * 4] = h0;
        *(half4v*)&Ah[buf][ar1][ac1 * 4] = h1;
        *(half8v*)&Bh[buf][bn0][bk0 * 8] = bR0;
        *(half8v*)&Bh[buf][bn1][bk1 * 8] = bR1;
    };

    load_regs(0);
    store_lds(0);
    __syncthreads();
#pragma unroll
    for (int ks = 0; ks < 8; ++ks) {
        int cur = ks & 1;
        if (ks < 7) load_regs((ks + 1) * 32);
        half8v a[2], b[4];
#pragma unroll
        for (int mf = 0; mf < 2; ++mf)
            a[mf] = *(const half8v*)&Ah[cur][wr * 32 + mf * 16 + lr][lg * 8];
#pragma unroll
        for (int nf = 0; nf < 4; ++nf)
            b[nf] = *(const half8v*)&Bh[cur][wc * 64 + nf * 16 + lr][lg * 8];
#pragma unroll
        for (int mf = 0; mf < 2; ++mf)
#pragma unroll
            for (int nf = 0; nf < 4; ++nf)
                acc[mf][nf] = __builtin_amdgcn_mfma_f32_16x16x32_f16(a[mf], b[nf], acc[mf][nf], 0, 0, 0);
        if (ks < 7) {
            __syncthreads();
            store_lds(cur ^ 1);
            __syncthreads();
        }
    }
    // epilogue -> blocked layout: chunk = gcol>>5, within-chunk col = gcol&31
#pragma unroll
    for (int mf = 0; mf < 2; ++mf) {
#pragma unroll
        for (int reg = 0; reg < 4; ++reg) {
            int gr = bm + wr * 32 + mf * 16 + lg * 4 + reg;
            if (gr < M) {
                float sc = dinv[gr];
#pragma unroll
                for (int nf = 0; nf < 4; ++nf) {
                    int gcol = bn + wc * 64 + nf * 16 + lr;
                    size_t cidx = (size_t)(gcol >> 5) * ((size_t)NN * CHW) +
                                  (size_t)gr * CHW + (gcol & 31);
                    C[cidx] = (_Float16)(acc[mf][nf][reg] * sc);
                }
            }
        }
    }
}

// ---------------- fused: deg_count + W1 transpose + tiny projections ----------------
__global__ __launch_bounds__(256) void deg_prep(const int* __restrict__ dst,
                                                int* __restrict__ deg,
                                                const float* __restrict__ W1,
                                                const float* __restrict__ W2,
                                                const float* __restrict__ fW1,
                                                const float* __restrict__ emb0,
                                                const float* __restrict__ emb1,
                                                _Float16* __restrict__ BT,
                                                float* __restrict__ Wft,
                                                float2* __restrict__ t0,
                                                float2* __restrict__ t1) {
    __shared__ float T[64][65];
    int b = blockIdx.x;
    int t = threadIdx.x;
    if (b < DEGB) {
        int e = b * 256 + t;
        if (e < EE) atomicAdd(&deg[dst[e]], 1);
    } else if (b < DEGB + 16) {
        int bb = b - DEGB;
        int k0 = (bb >> 2) * 64, n0 = (bb & 3) * 64;
#pragma unroll
        for (int i = 0; i < 16; ++i) {
            int r = i * 4 + (t >> 6), c = t & 63;
            T[r][c] = W1[(size_t)(k0 + r) * 256 + n0 + c];
        }
        __syncthreads();
#pragma unroll
        for (int i = 0; i < 16; ++i) {
            int n = i * 4 + (t >> 6), k = t & 63;
            BT[(size_t)(n0 + n) * 256 + k0 + k] = (_Float16)T[k][n];
        }
    } else {
        int k = t;
        float s0 = 0.f, s1 = 0.f;
        for (int m = 0; m < 128; ++m) {
            float wv = W2[(size_t)k * 128 + m];
            s0 += wv * fW1[m * 2 + 0];
            s1 += wv * fW1[m * 2 + 1];
        }
        Wft[k] = s0;
        Wft[256 + k] = s1;
        if (k < 20) {
            float a0 = 0.f, a1 = 0.f, b0 = 0.f, b1v = 0.f;
            for (int u = 0; u < 32; ++u) {
                float e0 = emb0[k * 32 + u], e1 = emb1[k * 32 + u];
                a0 += e0 * fW1[(130 + u) * 2 + 0];
                a1 += e0 * fW1[(130 + u) * 2 + 1];
                b0 += e1 * fW1[(162 + u) * 2 + 0];
                b1v += e1 * fW1[(162 + u) * 2 + 1];
            }
            t0[k] = make_float2(a0, a1);
            t1[k] = make_float2(b0, b1v);
        }
    }
}

// ---------------- 3-kernel parallel scan: deg -> rowptr (+ fused dinv) ----------------
__global__ __launch_bounds__(1024) void scan_partial(const int* __restrict__ deg,
                                                     int* __restrict__ rowptr,
                                                     int* __restrict__ bsum) {
    __shared__ int wsum[16];
    int tid = threadIdx.x, lane = tid & 63, w = tid >> 6;
    int idx = blockIdx.x * 1024 + tid;
    int v = (idx < NN) ? deg[idx] : 0;
    int x = v;
#pragma unroll
    for (int off = 1; off < 64; off <<= 1) {
        int t = __shfl_up(x, off, 64);
        if (lane >= off) x += t;
    }
    if (lane == 63) wsum[w] = x;
    __syncthreads();
    if (w == 0) {
        int s = (lane < 16) ? wsum[lane] : 0;
#pragma unroll
        for (int off = 1; off < 16; off <<= 1) {
            int t = __shfl_up(s, off, 64);
            if (lane >= off) s += t;
        }
        if (lane < 16) wsum[lane] = s;
    }
    __syncthreads();
    int wpre = (w == 0) ? 0 : wsum[w - 1];
    if (idx < NN) rowptr[idx] = wpre + (x - v);
    if (tid == 0) bsum[blockIdx.x] = wsum[15];
}

__global__ __launch_bounds__(64) void scan_bsum(int* __restrict__ bsum,
                                                int* __restrict__ rowptr) {
    int l = threadIdx.x;
    int v = (l < NB) ? bsum[l] : 0;
    int x = v;
#pragma unroll
    for (int off = 1; off < 64; off <<= 1) {
        int t = __shfl_up(x, off, 64);
        if (l >= off) x += t;
    }
    if (l < NB) bsum[l] = x - v;
    if (l == NB - 1) rowptr[NN] = x;
}

__global__ void scan_add_dinv(int* __restrict__ rowptr, const int* __restrict__ bsum,
                              const int* __restrict__ deg, float* __restrict__ dinv) {
    int idx = blockIdx.x * blockDim.x + threadIdx.x;
    if (idx < NN) {
        rowptr[idx] += bsum[idx >> 10];
        dinv[idx] = rsqrtf((float)deg[idx] + 1.0f);
    }
}

// ---------------- CSR bucket fill ----------------
__global__ void fill_csr(const int* __restrict__ src, const int* __restrict__ dst,
                         const int* __restrict__ rowptr, int* __restrict__ cursor,
                         int* __restrict__ csr_src) {
    int e = blockIdx.x * blockDim.x + threadIdx.x;
    if (e >= EE) return;
    int d = dst[e];
    int pos = atomicAdd(&cursor[d], 1);
    csr_src[rowptr[d] + pos] = src[e];
}

// ---------------- XCD-pinned chunked gather: chunk = blockIdx & 7 ----------------
// block: 8 nodes (4 waves x 2 halves); half = 32 feature-lanes, serial edge loop
__global__ __launch_bounds__(256) void gather_chunks(const _Float16* __restrict__ hs,
                                                     const int* __restrict__ rowptr,
                                                     const int* __restrict__ csr_src,
                                                     const float* __restrict__ dinv,
                                                     const float* __restrict__ b1,
                                                     const float* __restrict__ Wft,
                                                     float2* __restrict__ qpart) {
    int c = blockIdx.x & 7;                 // chunk -> pinned to one XCD (round-robin dispatch)
    int g = blockIdx.x >> 3;                // node group (NN/8 = 6250)
    int half = threadIdx.x >> 5;            // 0..7 node-slot within block
    int f = threadIdx.x & 31;               // feature lane
    int i = g * 8 + half;
    const _Float16* tab = hs + (size_t)c * NN * CHW;
    int start = rowptr[i], end = rowptr[i + 1];
    float acc = 0.f;
    int j = start;
    for (; j + 3 < end; j += 4) {
        int s0 = csr_src[j + 0];
        int s1 = csr_src[j + 1];
        int s2 = csr_src[j + 2];
        int s3 = csr_src[j + 3];
        float v0 = (float)tab[(size_t)s0 * CHW + f];
        float v1 = (float)tab[(size_t)s1 * CHW + f];
        float v2 = (float)tab[(size_t)s2 * CHW + f];
        float v3 = (float)tab[(size_t)s3 * CHW + f];
        acc += (v0 + v1) + (v2 + v3);
    }
    for (; j < end; ++j)
        acc += (float)tab[(size_t)csr_src[j] * CHW + f];
    float di = dinv[i];
    float self = (float)tab[(size_t)i * CHW + f];
    int fb = c * CHW + f;
    float o = fmaxf((acc + self) * di + b1[fb], 0.f);
    float q0 = o * Wft[fb];
    float q1 = o * Wft[256 + fb];
#pragma unroll
    for (int m = 16; m > 0; m >>= 1) {
        q0 += __shfl_xor(q0, m, 32);
        q1 += __shfl_xor(q1, m, 32);
    }
    if (f == 0) qpart[(size_t)c * NN + i] = make_float2(q0, q1);
}

// ---------------- q[i] = dinv[i] * sum_c qpart[c][i] ----------------
__global__ void reduce_q(const float2* __restrict__ qpart, const float* __restrict__ dinv,
                         float2* __restrict__ q) {
    int i = blockIdx.x * blockDim.x + threadIdx.x;
    if (i >= NN) return;
    float a = 0.f, b = 0.f;
#pragma unroll
    for (int c = 0; c < NCH; ++c) {
        float2 v = qpart[(size_t)c * NN + i];
        a += v.x;
        b += v.y;
    }
    float di = dinv[i];
    q[i] = make_float2(a * di, b * di);
}

// ---------------- gn[i] = (sum_j q[j] + q[i]) * dinv[i] ----------------
__global__ __launch_bounds__(256) void gather_gn(const float2* __restrict__ q,
                                                 const int* __restrict__ rowptr,
                                                 const int* __restrict__ csr_src,
                                                 const float* __restrict__ dinv,
                                                 float2* __restrict__ gn) {
    int i = blockIdx.x * blockDim.x + threadIdx.x;
    if (i >= NN) return;
    int start = rowptr[i], end = rowptr[i + 1];
    float a0 = 0.f, a1 = 0.f;
    for (int j = start; j < end; ++j) {
        float2 v = q[csr_src[j]];
        a0 += v.x;
        a1 += v.y;
    }
    float2 self = q[i];
    float di = dinv[i];
    gn[i] = make_float2((a0 + self.x) * di, (a1 + self.y) * di);
}

// ---------------- final edge kernel ----------------
__global__ __launch_bounds__(256) void edge_out(const float2* __restrict__ gn,
                                                const int* __restrict__ src,
                                                const int* __restrict__ dst,
                                                const int2* __restrict__ ecat,
                                                const float2* __restrict__ ev,
                                                const float* __restrict__ fW1,
                                                const float2* __restrict__ t0,
                                                const float2* __restrict__ t1,
                                                const float* __restrict__ fb1,
                                                const float* __restrict__ fW2,
                                                const float* __restrict__ fb2,
                                                float2* __restrict__ out) {
    int e = blockIdx.x * blockDim.x + threadIdx.x;
    if (e >= EE) return;
    int s = src[e], d = dst[e];
    float2 gs = gn[s], gd = gn[d];
    int2 c = ecat[e];
    float2 v = ev[e];
    float2 e0 = t0[c.x], e1 = t1[c.y];
    float z0 = gs.x - gd.x + v.x * fW1[128 * 2 + 0] + v.y * fW1[129 * 2 + 0] + e0.x + e1.x;
    float z1 = gs.y - gd.y + v.x * fW1[128 * 2 + 1] + v.y * fW1[129 * 2 + 1] + e0.y + e1.y;
    float y0 = fmaxf(z0 + fb1[0], 0.f);
    float y1 = fmaxf(z1 + fb1[1], 0.f);
    out[e] = make_float2(y0 * fW2[0] + y1 * fW2[2] + fb2[0],
                         y0 * fW2[1] + y1 * fW2[3] + fb2[1]);
}

extern "C" void kernel_launch(void* const* d_in, const int* in_sizes, int n_in,
                              void* d_out, int out_size, void* d_ws, size_t ws_size,
                              hipStream_t stream) {
    const float* x    = (const float*)d_in[0];
    const int*   eidx = (const int*)d_in[1];
    const int*   src  = eidx;
    const int*   dst  = eidx + EE;
    const int*   ecat = (const int*)d_in[2];
    const float* ev   = (const float*)d_in[3];
    const float* W1   = (const float*)d_in[4];
    const float* b1   = (const float*)d_in[5];
    const float* W2   = (const float*)d_in[6];
    // b2 (d_in[7]) cancels in gn[s]-gn[d]; unused.
    const float* emb0 = (const float*)d_in[8];
    const float* emb1 = (const float*)d_in[9];
    const float* fW1  = (const float*)d_in[10];
    const float* fb1  = (const float*)d_in[11];
    const float* fW2  = (const float*)d_in[12];
    const float* fb2  = (const float*)d_in[13];
    float* out = (float*)d_out;

    char* ws = (char*)d_ws;
    size_t off = 0;
    auto alloc = [&](size_t bytes) {
        void* p = ws + off;
        off = (off + bytes + 255) & ~(size_t)255;
        return p;
    };
    int*      deg     = (int*)alloc((size_t)NN * 4);      // deg+cursor adjacent: one memset
    int*      cursor  = (int*)alloc((size_t)NN * 4);
    float*    dinv    = (float*)alloc((size_t)NN * 4);
    int*      rowptr  = (int*)alloc((size_t)(NN + 1) * 4);
    int*      bsum    = (int*)alloc((size_t)NB * 4);
    int*      csr_src = (int*)alloc((size_t)EE * 4);
    _Float16* W1T     = (_Float16*)alloc((size_t)256 * 256 * 2);
    _Float16* h1s     = (_Float16*)alloc((size_t)NN * 256 * 2);   // blocked [8][NN][32]
    float2*   qpart   = (float2*)alloc((size_t)NCH * NN * 8);
    float2*   q       = (float2*)alloc((size_t)NN * 8);
    float2*   gn      = (float2*)alloc((size_t)NN * 8);
    float*    Wft     = (float*)alloc(512 * 4);
    float2*   t0      = (float2*)alloc(20 * 8);
    float2*   t1      = (float2*)alloc(20 * 8);

    hipMemsetAsync(deg, 0, (size_t)((char*)cursor - (char*)deg) + (size_t)NN * 4, stream);

    deg_prep<<<DEGB + 17, 256, 0, stream>>>(dst, deg, W1, W2, fW1, emb0, emb1,
                                            W1T, Wft, t0, t1);
    scan_partial<<<NB, 1024, 0, stream>>>(deg, rowptr, bsum);
    scan_bsum<<<1, 64, 0, stream>>>(bsum, rowptr);
    scan_add_dinv<<<(NN + 255) / 256, 256, 0, stream>>>(rowptr, bsum, deg, dinv);
    fill_csr<<<(EE + 255) / 256, 256, 0, stream>>>(src, dst, rowptr, cursor, csr_src);

    // layer 1 GEMM (MFMA fp16, dbuf), blocked-chunk output
    {
        dim3 g(2, (NN + 63) / 64);
        gemm1_mfma<<<g, 256, 0, stream>>>(x, W1T, dinv, h1s, NN);
    }
    // XCD-pinned chunked gather -> qpart
    gather_chunks<<<NCH * (NN / 8), 256, 0, stream>>>(h1s, rowptr, csr_src, dinv, b1, Wft, qpart);
    // q = dinv * sum_c qpart
    reduce_q<<<(NN + 255) / 256, 256, 0, stream>>>(qpart, dinv, q);
    // gn
    gather_gn<<<(NN + 255) / 256, 256, 0, stream>>>(q, rowptr, csr_src, dinv, gn);
    // edges
    edge_out<<<(EE + 255) / 256, 256, 0, stream>>>(
        gn, src, dst, (const int2*)ecat, (const float2*)ev,
        fW1, t0, t1, fb1, fW2, fb2, (float2*)out);
}

// Round 10
// 243.917 us; speedup vs baseline: 1.0434x; 1.0434x over previous
//
#include <hip/hip_runtime.h>

#define NN 50000
#define EE 800000
#define NB ((NN + 1023) / 1024)   // 49 scan blocks
#define DEGB ((EE + 255) / 256)   // 3125 deg-count blocks
#define NCH 8
#define CHW 32

typedef _Float16 half8v __attribute__((ext_vector_type(8)));
typedef _Float16 half4v __attribute__((ext_vector_type(4)));
typedef float f32x4 __attribute__((ext_vector_type(4)));

// ---------------- MFMA fp16 GEMM, double-buffered; blocked output [8][NN][32] ----------------
__global__ __launch_bounds__(256) void gemm1_mfma(const float* __restrict__ A,
                                                  const _Float16* __restrict__ BT,
                                                  const float* __restrict__ dinv,
                                                  _Float16* __restrict__ C, int M) {
    __shared__ _Float16 Ah[2][64][40];
    __shared__ _Float16 Bh[2][128][40];
    int tid = threadIdx.x;
    int bm = blockIdx.y * 64, bn = blockIdx.x * 128;
    int w = tid >> 6, l = tid & 63;
    int wr = w >> 1, wc = w & 1;
    int lr = l & 15, lg = l >> 4;
    int ar0 = tid >> 3, ac0 = tid & 7;
    int ar1 = (tid + 256) >> 3, ac1 = (tid + 256) & 7;
    int bn0 = tid >> 2, bk0 = tid & 3;
    int bn1 = (tid + 256) >> 2, bk1 = (tid + 256) & 3;
    f32x4 acc[2][4] = {};
    float4 aR0, aR1;
    half8v bR0, bR1;

    auto load_regs = [&](int k0) {
        int gm0 = bm + ar0, gm1 = bm + ar1;
        aR0 = (gm0 < M) ? *(const float4*)&A[(size_t)gm0 * 256 + k0 + ac0 * 4]
                        : make_float4(0.f, 0.f, 0.f, 0.f);
        aR1 = (gm1 < M) ? *(const float4*)&A[(size_t)gm1 * 256 + k0 + ac1 * 4]
                        : make_float4(0.f, 0.f, 0.f, 0.f);
        bR0 = *(const half8v*)&BT[(size_t)(bn + bn0) * 256 + k0 + bk0 * 8];
        bR1 = *(const half8v*)&BT[(size_t)(bn + bn1) * 256 + k0 + bk1 * 8];
    };
    auto store_lds = [&](int buf) {
        half4v h0, h1;
        h0[0] = (_Float16)aR0.x; h0[1] = (_Float16)aR0.y;
        h0[2] = (_Float16)aR0.z; h0[3] = (_Float16)aR0.w;
        h1[0] = (_Float16)aR1.x; h1[1] = (_Float16)aR1.y;
        h1[2] = (_Float16)aR1.z; h1[3] = (_Float16)aR1.w;
        *(half4v*)&Ah[buf][ar0][ac0 * 4] = h0;
        *(half4v*)&Ah[buf][ar1][ac1 * 4] = h1;
        *(half8v*)&Bh[buf][bn0][bk0 * 8] = bR0;
        *(half8v*)&Bh[buf][bn1][bk1 * 8] = bR1;
    };

    load_regs(0);
    store_lds(0);
    __syncthreads();
#pragma unroll
    for (int ks = 0; ks < 8; ++ks) {
        int cur = ks & 1;
        if (ks < 7) load_regs((ks + 1) * 32);
        half8v a[2], b[4];
#pragma unroll
        for (int mf = 0; mf < 2; ++mf)
            a[mf] = *(const half8v*)&Ah[cur][wr * 32 + mf * 16 + lr][lg * 8];
#pragma unroll
        for (int nf = 0; nf < 4; ++nf)
            b[nf] = *(const half8v*)&Bh[cur][wc * 64 + nf * 16 + lr][lg * 8];
#pragma unroll
        for (int mf = 0; mf < 2; ++mf)
#pragma unroll
            for (int nf = 0; nf < 4; ++nf)
                acc[mf][nf] = __builtin_amdgcn_mfma_f32_16x16x32_f16(a[mf], b[nf], acc[mf][nf], 0, 0, 0);
        if (ks < 7) {
            __syncthreads();
            store_lds(cur ^ 1);
            __syncthreads();
        }
    }
    // epilogue -> blocked layout: chunk = gcol>>5, within-chunk col = gcol&31
#pragma unroll
    for (int mf = 0; mf < 2; ++mf) {
#pragma unroll
        for (int reg = 0; reg < 4; ++reg) {
            int gr = bm + wr * 32 + mf * 16 + lg * 4 + reg;
            if (gr < M) {
                float sc = dinv[gr];
#pragma unroll
                for (int nf = 0; nf < 4; ++nf) {
                    int gcol = bn + wc * 64 + nf * 16 + lr;
                    size_t cidx = (size_t)(gcol >> 5) * ((size_t)NN * CHW) +
                                  (size_t)gr * CHW + (gcol & 31);
                    C[cidx] = (_Float16)(acc[mf][nf][reg] * sc);
                }
            }
        }
    }
}

// ---------------- fused: deg_count + W1 transpose + tiny projections ----------------
__global__ __launch_bounds__(256) void deg_prep(const int* __restrict__ dst,
                                                int* __restrict__ deg,
                                                const float* __restrict__ W1,
                                                const float* __restrict__ W2,
                                                const float* __restrict__ fW1,
                                                const float* __restrict__ emb0,
                                                const float* __restrict__ emb1,
                                                _Float16* __restrict__ BT,
                                                float* __restrict__ Wft,
                                                float2* __restrict__ t0,
                                                float2* __restrict__ t1) {
    __shared__ float T[64][65];
    int b = blockIdx.x;
    int t = threadIdx.x;
    if (b < DEGB) {
        int e = b * 256 + t;
        if (e < EE) atomicAdd(&deg[dst[e]], 1);
    } else if (b < DEGB + 16) {
        int bb = b - DEGB;
        int k0 = (bb >> 2) * 64, n0 = (bb & 3) * 64;
#pragma unroll
        for (int i = 0; i < 16; ++i) {
            int r = i * 4 + (t >> 6), c = t & 63;
            T[r][c] = W1[(size_t)(k0 + r) * 256 + n0 + c];
        }
        __syncthreads();
#pragma unroll
        for (int i = 0; i < 16; ++i) {
            int n = i * 4 + (t >> 6), k = t & 63;
            BT[(size_t)(n0 + n) * 256 + k0 + k] = (_Float16)T[k][n];
        }
    } else {
        int k = t;
        float s0 = 0.f, s1 = 0.f;
        for (int m = 0; m < 128; ++m) {
            float wv = W2[(size_t)k * 128 + m];
            s0 += wv * fW1[m * 2 + 0];
            s1 += wv * fW1[m * 2 + 1];
        }
        Wft[k] = s0;
        Wft[256 + k] = s1;
        if (k < 20) {
            float a0 = 0.f, a1 = 0.f, b0 = 0.f, b1v = 0.f;
            for (int u = 0; u < 32; ++u) {
                float e0 = emb0[k * 32 + u], e1 = emb1[k * 32 + u];
                a0 += e0 * fW1[(130 + u) * 2 + 0];
                a1 += e0 * fW1[(130 + u) * 2 + 1];
                b0 += e1 * fW1[(162 + u) * 2 + 0];
                b1v += e1 * fW1[(162 + u) * 2 + 1];
            }
            t0[k] = make_float2(a0, a1);
            t1[k] = make_float2(b0, b1v);
        }
    }
}

// ---------------- 3-kernel parallel scan: deg -> rowptr (+ fused dinv) ----------------
__global__ __launch_bounds__(1024) void scan_partial(const int* __restrict__ deg,
                                                     int* __restrict__ rowptr,
                                                     int* __restrict__ bsum) {
    __shared__ int wsum[16];
    int tid = threadIdx.x, lane = tid & 63, w = tid >> 6;
    int idx = blockIdx.x * 1024 + tid;
    int v = (idx < NN) ? deg[idx] : 0;
    int x = v;
#pragma unroll
    for (int off = 1; off < 64; off <<= 1) {
        int t = __shfl_up(x, off, 64);
        if (lane >= off) x += t;
    }
    if (lane == 63) wsum[w] = x;
    __syncthreads();
    if (w == 0) {
        int s = (lane < 16) ? wsum[lane] : 0;
#pragma unroll
        for (int off = 1; off < 16; off <<= 1) {
            int t = __shfl_up(s, off, 64);
            if (lane >= off) s += t;
        }
        if (lane < 16) wsum[lane] = s;
    }
    __syncthreads();
    int wpre = (w == 0) ? 0 : wsum[w - 1];
    if (idx < NN) rowptr[idx] = wpre + (x - v);
    if (tid == 0) bsum[blockIdx.x] = wsum[15];
}

__global__ __launch_bounds__(64) void scan_bsum(int* __restrict__ bsum,
                                                int* __restrict__ rowptr) {
    int l = threadIdx.x;
    int v = (l < NB) ? bsum[l] : 0;
    int x = v;
#pragma unroll
    for (int off = 1; off < 64; off <<= 1) {
        int t = __shfl_up(x, off, 64);
        if (l >= off) x += t;
    }
    if (l < NB) bsum[l] = x - v;
    if (l == NB - 1) rowptr[NN] = x;
}

__global__ void scan_add_dinv(int* __restrict__ rowptr, const int* __restrict__ bsum,
                              const int* __restrict__ deg, float* __restrict__ dinv) {
    int idx = blockIdx.x * blockDim.x + threadIdx.x;
    if (idx < NN) {
        rowptr[idx] += bsum[idx >> 10];
        dinv[idx] = rsqrtf((float)deg[idx] + 1.0f);
    }
}

// ---------------- CSR bucket fill ----------------
__global__ void fill_csr(const int* __restrict__ src, const int* __restrict__ dst,
                         const int* __restrict__ rowptr, int* __restrict__ cursor,
                         int* __restrict__ csr_src) {
    int e = blockIdx.x * blockDim.x + threadIdx.x;
    if (e >= EE) return;
    int d = dst[e];
    int pos = atomicAdd(&cursor[d], 1);
    csr_src[rowptr[d] + pos] = src[e];
}

// ---------------- XCD-pinned chunked gather, vectorized ----------------
// chunk = blockIdx & 7 (pins each 3.2MB slice to one XCD's L2)
// 32 lanes per node: 4 edge-slots x 8 feature-lanes, half4v (8B) loads
__global__ __launch_bounds__(256) void gather_chunks(const _Float16* __restrict__ hs,
                                                     const int* __restrict__ rowptr,
                                                     const int* __restrict__ csr_src,
                                                     const float* __restrict__ dinv,
                                                     const float* __restrict__ b1,
                                                     const float* __restrict__ Wft,
                                                     float2* __restrict__ qpart) {
    int c = blockIdx.x & 7;
    int g = blockIdx.x >> 3;
    int ns = threadIdx.x >> 5;          // node slot 0..7
    int L = threadIdx.x & 31;
    int slot = L >> 3, fo = L & 7;      // edge-slot, feature-octet
    int i = g * 8 + ns;
    const _Float16* tab = hs + (size_t)c * NN * CHW;
    int start = rowptr[i], end = rowptr[i + 1];
    float a0 = 0.f, a1 = 0.f, a2 = 0.f, a3 = 0.f;
    for (int j = start; j < end; j += 4) {
        int idx = j + slot;
        if (idx < end) {
            int s = csr_src[idx];
            half4v v = *(const half4v*)(tab + (size_t)s * CHW + fo * 4);
            a0 += (float)v[0];
            a1 += (float)v[1];
            a2 += (float)v[2];
            a3 += (float)v[3];
        }
    }
    // reduce across the 4 edge-slots (lane bits 3,4)
    a0 += __shfl_xor(a0, 8);  a1 += __shfl_xor(a1, 8);
    a2 += __shfl_xor(a2, 8);  a3 += __shfl_xor(a3, 8);
    a0 += __shfl_xor(a0, 16); a1 += __shfl_xor(a1, 16);
    a2 += __shfl_xor(a2, 16); a3 += __shfl_xor(a3, 16);
    float di = dinv[i];
    half4v sv = *(const half4v*)(tab + (size_t)i * CHW + fo * 4);
    int fb = c * CHW + fo * 4;
    float4 bb = *(const float4*)&b1[fb];
    float4 w0 = *(const float4*)&Wft[fb];
    float4 w1 = *(const float4*)&Wft[256 + fb];
    float o0 = fmaxf((a0 + (float)sv[0]) * di + bb.x, 0.f);
    float o1 = fmaxf((a1 + (float)sv[1]) * di + bb.y, 0.f);
    float o2 = fmaxf((a2 + (float)sv[2]) * di + bb.z, 0.f);
    float o3 = fmaxf((a3 + (float)sv[3]) * di + bb.w, 0.f);
    float q0 = o0 * w0.x + o1 * w0.y + o2 * w0.z + o3 * w0.w;
    float q1 = o0 * w1.x + o1 * w1.y + o2 * w1.z + o3 * w1.w;
    // reduce across the 8 feature-octets (lane bits 0-2)
    q0 += __shfl_xor(q0, 1); q1 += __shfl_xor(q1, 1);
    q0 += __shfl_xor(q0, 2); q1 += __shfl_xor(q1, 2);
    q0 += __shfl_xor(q0, 4); q1 += __shfl_xor(q1, 4);
    if (L == 0) qpart[(size_t)c * NN + i] = make_float2(q0, q1);
}

// ---------------- q[i] = dinv[i] * sum_c qpart[c][i] ----------------
__global__ void reduce_q(const float2* __restrict__ qpart, const float* __restrict__ dinv,
                         float2* __restrict__ q) {
    int i = blockIdx.x * blockDim.x + threadIdx.x;
    if (i >= NN) return;
    float a = 0.f, b = 0.f;
#pragma unroll
    for (int c = 0; c < NCH; ++c) {
        float2 v = qpart[(size_t)c * NN + i];
        a += v.x;
        b += v.y;
    }
    float di = dinv[i];
    q[i] = make_float2(a * di, b * di);
}

// ---------------- gn[i] = (sum_j q[j] + q[i]) * dinv[i] ----------------
__global__ __launch_bounds__(256) void gather_gn(const float2* __restrict__ q,
                                                 const int* __restrict__ rowptr,
                                                 const int* __restrict__ csr_src,
                                                 const float* __restrict__ dinv,
                                                 float2* __restrict__ gn) {
    int i = blockIdx.x * blockDim.x + threadIdx.x;
    if (i >= NN) return;
    int start = rowptr[i], end = rowptr[i + 1];
    float a0 = 0.f, a1 = 0.f;
    for (int j = start; j < end; ++j) {
        float2 v = q[csr_src[j]];
        a0 += v.x;
        a1 += v.y;
    }
    float2 self = q[i];
    float di = dinv[i];
    gn[i] = make_float2((a0 + self.x) * di, (a1 + self.y) * di);
}

// ---------------- final edge kernel ----------------
__global__ __launch_bounds__(256) void edge_out(const float2* __restrict__ gn,
                                                const int* __restrict__ src,
                                                const int* __restrict__ dst,
                                                const int2* __restrict__ ecat,
                                                const float2* __restrict__ ev,
                                                const float* __restrict__ fW1,
                                                const float2* __restrict__ t0,
                                                const float2* __restrict__ t1,
                                                const float* __restrict__ fb1,
                                                const float* __restrict__ fW2,
                                                const float* __restrict__ fb2,
                                                float2* __restrict__ out) {
    int e = blockIdx.x * blockDim.x + threadIdx.x;
    if (e >= EE) return;
    int s = src[e], d = dst[e];
    float2 gs = gn[s], gd = gn[d];
    int2 c = ecat[e];
    float2 v = ev[e];
    float2 e0 = t0[c.x], e1 = t1[c.y];
    float z0 = gs.x - gd.x + v.x * fW1[128 * 2 + 0] + v.y * fW1[129 * 2 + 0] + e0.x + e1.x;
    float z1 = gs.y - gd.y + v.x * fW1[128 * 2 + 1] + v.y * fW1[129 * 2 + 1] + e0.y + e1.y;
    float y0 = fmaxf(z0 + fb1[0], 0.f);
    float y1 = fmaxf(z1 + fb1[1], 0.f);
    out[e] = make_float2(y0 * fW2[0] + y1 * fW2[2] + fb2[0],
                         y0 * fW2[1] + y1 * fW2[3] + fb2[1]);
}

extern "C" void kernel_launch(void* const* d_in, const int* in_sizes, int n_in,
                              void* d_out, int out_size, void* d_ws, size_t ws_size,
                              hipStream_t stream) {
    const float* x    = (const float*)d_in[0];
    const int*   eidx = (const int*)d_in[1];
    const int*   src  = eidx;
    const int*   dst  = eidx + EE;
    const int*   ecat = (const int*)d_in[2];
    const float* ev   = (const float*)d_in[3];
    const float* W1   = (const float*)d_in[4];
    const float* b1   = (const float*)d_in[5];
    const float* W2   = (const float*)d_in[6];
    // b2 (d_in[7]) cancels in gn[s]-gn[d]; unused.
    const float* emb0 = (const float*)d_in[8];
    const float* emb1 = (const float*)d_in[9];
    const float* fW1  = (const float*)d_in[10];
    const float* fb1  = (const float*)d_in[11];
    const float* fW2  = (const float*)d_in[12];
    const float* fb2  = (const float*)d_in[13];
    float* out = (float*)d_out;

    char* ws = (char*)d_ws;
    size_t off = 0;
    auto alloc = [&](size_t bytes) {
        void* p = ws + off;
        off = (off + bytes + 255) & ~(size_t)255;
        return p;
    };
    int*      deg     = (int*)alloc((size_t)NN * 4);      // deg+cursor adjacent: one memset
    int*      cursor  = (int*)alloc((size_t)NN * 4);
    float*    dinv    = (float*)alloc((size_t)NN * 4);
    int*      rowptr  = (int*)alloc((size_t)(NN + 1) * 4);
    int*      bsum    = (int*)alloc((size_t)NB * 4);
    int*      csr_src = (int*)alloc((size_t)EE * 4);
    _Float16* W1T     = (_Float16*)alloc((size_t)256 * 256 * 2);
    _Float16* h1s     = (_Float16*)alloc((size_t)NN * 256 * 2);   // blocked [8][NN][32]
    float2*   qpart   = (float2*)alloc((size_t)NCH * NN * 8);
    float2*   q       = (float2*)alloc((size_t)NN * 8);
    float2*   gn      = (float2*)alloc((size_t)NN * 8);
    float*    Wft     = (float*)alloc(512 * 4);
    float2*   t0      = (float2*)alloc(20 * 8);
    float2*   t1      = (float2*)alloc(20 * 8);

    hipMemsetAsync(deg, 0, (size_t)((char*)cursor - (char*)deg) + (size_t)NN * 4, stream);

    deg_prep<<<DEGB + 17, 256, 0, stream>>>(dst, deg, W1, W2, fW1, emb0, emb1,
                                            W1T, Wft, t0, t1);
    scan_partial<<<NB, 1024, 0, stream>>>(deg, rowptr, bsum);
    scan_bsum<<<1, 64, 0, stream>>>(bsum, rowptr);
    scan_add_dinv<<<(NN + 255) / 256, 256, 0, stream>>>(rowptr, bsum, deg, dinv);
    fill_csr<<<(EE + 255) / 256, 256, 0, stream>>>(src, dst, rowptr, cursor, csr_src);

    // layer 1 GEMM (MFMA fp16, dbuf), blocked-chunk output
    {
        dim3 g(2, (NN + 63) / 64);
        gemm1_mfma<<<g, 256, 0, stream>>>(x, W1T, dinv, h1s, NN);
    }
    // XCD-pinned chunked gather -> qpart
    gather_chunks<<<NCH * (NN / 8), 256, 0, stream>>>(h1s, rowptr, csr_src, dinv, b1, Wft, qpart);
    // q = dinv * sum_c qpart
    reduce_q<<<(NN + 255) / 256, 256, 0, stream>>>(qpart, dinv, q);
    // gn
    gather_gn<<<(NN + 255) / 256, 256, 0, stream>>>(q, rowptr, csr_src, dinv, gn);
    // edges
    edge_out<<<(EE + 255) / 256, 256, 0, stream>>>(
        gn, src, dst, (const int2*)ecat, (const float2*)ev,
        fW1, t0, t1, fb1, fW2, fb2, (float2*)out);
}

// Round 11
// 165.249 us; speedup vs baseline: 1.5401x; 1.4761x over previous
//
#include <hip/hip_runtime.h>

#define NN 50000
#define EE 800000
#define NB ((NN + 1023) / 1024)   // 49 scan blocks
#define DEGB ((EE + 255) / 256)   // 3125 edge-parallel blocks
#define GEMMB (2 * ((NN + 63) / 64))  // 1564 gemm tile blocks

typedef _Float16 half8v __attribute__((ext_vector_type(8)));
typedef _Float16 half4v __attribute__((ext_vector_type(4)));
typedef float f32x4 __attribute__((ext_vector_type(4)));

// ---------------- prep: W1 transpose->fp16 (blocks 0..15) + tiny projections (block 16) ------
__global__ __launch_bounds__(256) void prep(const float* __restrict__ W1,
                                            const float* __restrict__ W2,
                                            const float* __restrict__ fW1,
                                            const float* __restrict__ emb0,
                                            const float* __restrict__ emb1,
                                            _Float16* __restrict__ BT,
                                            float* __restrict__ Wft,
                                            float2* __restrict__ t0,
                                            float2* __restrict__ t1) {
    int b = blockIdx.x;
    int t = threadIdx.x;
    if (b < 16) {
        __shared__ float T[64][65];
        int k0 = (b >> 2) * 64, n0 = (b & 3) * 64;
#pragma unroll
        for (int i = 0; i < 16; ++i) {
            int r = i * 4 + (t >> 6), c = t & 63;
            T[r][c] = W1[(size_t)(k0 + r) * 256 + n0 + c];
        }
        __syncthreads();
#pragma unroll
        for (int i = 0; i < 16; ++i) {
            int n = i * 4 + (t >> 6), k = t & 63;
            BT[(size_t)(n0 + n) * 256 + k0 + k] = (_Float16)T[k][n];
        }
    } else {
        int k = t;
        float s0 = 0.f, s1 = 0.f;
        for (int m = 0; m < 128; ++m) {
            float wv = W2[(size_t)k * 128 + m];
            s0 += wv * fW1[m * 2 + 0];
            s1 += wv * fW1[m * 2 + 1];
        }
        Wft[k] = s0;
        Wft[256 + k] = s1;
        if (k < 20) {
            float a0 = 0.f, a1 = 0.f, b0 = 0.f, b1v = 0.f;
            for (int u = 0; u < 32; ++u) {
                float e0 = emb0[k * 32 + u], e1 = emb1[k * 32 + u];
                a0 += e0 * fW1[(130 + u) * 2 + 0];
                a1 += e0 * fW1[(130 + u) * 2 + 1];
                b0 += e1 * fW1[(162 + u) * 2 + 0];
                b1v += e1 * fW1[(162 + u) * 2 + 1];
            }
            t0[k] = make_float2(a0, a1);
            t1[k] = make_float2(b0, b1v);
        }
    }
}

// ---------------- fused: MFMA fp16 GEMM (blocks 0..GEMMB-1) + deg_count/epos (rest) ----------
// gemm: h1[M,256] = fp16(A[M,256] @ W1), graph-independent (dinv applied later in gather)
__global__ __launch_bounds__(256) void gemm_deg(const float* __restrict__ A,
                                                const _Float16* __restrict__ BT,
                                                _Float16* __restrict__ C, int M,
                                                const int* __restrict__ dst,
                                                int* __restrict__ deg,
                                                int* __restrict__ epos) {
    if (blockIdx.x >= GEMMB) {
        int e = (blockIdx.x - GEMMB) * 256 + threadIdx.x;
        if (e < EE) epos[e] = atomicAdd(&deg[dst[e]], 1);
        return;
    }
    __shared__ _Float16 Ah[2][64][40];
    __shared__ _Float16 Bh[2][128][40];
    int tid = threadIdx.x;
    int bm = (blockIdx.x >> 1) * 64, bn = (blockIdx.x & 1) * 128;
    int w = tid >> 6, l = tid & 63;
    int wr = w >> 1, wc = w & 1;
    int lr = l & 15, lg = l >> 4;
    int ar0 = tid >> 3, ac0 = tid & 7;
    int ar1 = (tid + 256) >> 3, ac1 = (tid + 256) & 7;
    int bn0 = tid >> 2, bk0 = tid & 3;
    int bn1 = (tid + 256) >> 2, bk1 = (tid + 256) & 3;
    f32x4 acc[2][4] = {};
    float4 aR0, aR1;
    half8v bR0, bR1;

    auto load_regs = [&](int k0) {
        int gm0 = bm + ar0, gm1 = bm + ar1;
        aR0 = (gm0 < M) ? *(const float4*)&A[(size_t)gm0 * 256 + k0 + ac0 * 4]
                        : make_float4(0.f, 0.f, 0.f, 0.f);
        aR1 = (gm1 < M) ? *(const float4*)&A[(size_t)gm1 * 256 + k0 + ac1 * 4]
                        : make_float4(0.f, 0.f, 0.f, 0.f);
        bR0 = *(const half8v*)&BT[(size_t)(bn + bn0) * 256 + k0 + bk0 * 8];
        bR1 = *(const half8v*)&BT[(size_t)(bn + bn1) * 256 + k0 + bk1 * 8];
    };
    auto store_lds = [&](int buf) {
        half4v h0, h1;
        h0[0] = (_Float16)aR0.x; h0[1] = (_Float16)aR0.y;
        h0[2] = (_Float16)aR0.z; h0[3] = (_Float16)aR0.w;
        h1[0] = (_Float16)aR1.x; h1[1] = (_Float16)aR1.y;
        h1[2] = (_Float16)aR1.z; h1[3] = (_Float16)aR1.w;
        *(half4v*)&Ah[buf][ar0][ac0 * 4] = h0;
        *(half4v*)&Ah[buf][ar1][ac1 * 4] = h1;
        *(half8v*)&Bh[buf][bn0][bk0 * 8] = bR0;
        *(half8v*)&Bh[buf][bn1][bk1 * 8] = bR1;
    };

    load_regs(0);
    store_lds(0);
    __syncthreads();
#pragma unroll
    for (int ks = 0; ks < 8; ++ks) {
        int cur = ks & 1;
        if (ks < 7) load_regs((ks + 1) * 32);
        half8v a[2], b[4];
#pragma unroll
        for (int mf = 0; mf < 2; ++mf)
            a[mf] = *(const half8v*)&Ah[cur][wr * 32 + mf * 16 + lr][lg * 8];
#pragma unroll
        for (int nf = 0; nf < 4; ++nf)
            b[nf] = *(const half8v*)&Bh[cur][wc * 64 + nf * 16 + lr][lg * 8];
#pragma unroll
        for (int mf = 0; mf < 2; ++mf)
#pragma unroll
            for (int nf = 0; nf < 4; ++nf)
                acc[mf][nf] = __builtin_amdgcn_mfma_f32_16x16x32_f16(a[mf], b[nf], acc[mf][nf], 0, 0, 0);
        if (ks < 7) {
            __syncthreads();
            store_lds(cur ^ 1);
            __syncthreads();
        }
    }
#pragma unroll
    for (int mf = 0; mf < 2; ++mf) {
#pragma unroll
        for (int reg = 0; reg < 4; ++reg) {
            int gr = bm + wr * 32 + mf * 16 + lg * 4 + reg;
            if (gr < M) {
#pragma unroll
                for (int nf = 0; nf < 4; ++nf)
                    C[(size_t)gr * 256 + bn + wc * 64 + nf * 16 + lr] =
                        (_Float16)acc[mf][nf][reg];
            }
        }
    }
}

// ---------------- scan phase 1: per-block exclusive scan of deg -> rowptr, block sums --------
__global__ __launch_bounds__(1024) void scan_partial(const int* __restrict__ deg,
                                                     int* __restrict__ rowptr,
                                                     int* __restrict__ bsum) {
    __shared__ int wsum[16];
    int tid = threadIdx.x, lane = tid & 63, w = tid >> 6;
    int idx = blockIdx.x * 1024 + tid;
    int v = (idx < NN) ? deg[idx] : 0;
    int x = v;
#pragma unroll
    for (int off = 1; off < 64; off <<= 1) {
        int t = __shfl_up(x, off, 64);
        if (lane >= off) x += t;
    }
    if (lane == 63) wsum[w] = x;
    __syncthreads();
    if (w == 0) {
        int s = (lane < 16) ? wsum[lane] : 0;
#pragma unroll
        for (int off = 1; off < 16; off <<= 1) {
            int t = __shfl_up(s, off, 64);
            if (lane >= off) s += t;
        }
        if (lane < 16) wsum[lane] = s;
    }
    __syncthreads();
    int wpre = (w == 0) ? 0 : wsum[w - 1];
    if (idx < NN) rowptr[idx] = wpre + (x - v);
    if (tid == 0) bsum[blockIdx.x] = wsum[15];
}

// ---------------- scan phase 2: in-block bsum prefix + add + dinv (+rowptr[NN]) --------------
__global__ __launch_bounds__(256) void scan_add_dinv(int* __restrict__ rowptr,
                                                     const int* __restrict__ bsum,
                                                     const int* __restrict__ deg,
                                                     float* __restrict__ dinv) {
    __shared__ int pre[NB + 1];
    int t = threadIdx.x;
    if (t < 64) {
        int v = (t < NB) ? bsum[t] : 0;
        int x = v;
#pragma unroll
        for (int o = 1; o < 64; o <<= 1) {
            int y = __shfl_up(x, o, 64);
            if (t >= o) x += y;
        }
        if (t < NB) pre[t] = x - v;
        if (t == NB - 1) pre[NB] = x;
    }
    __syncthreads();
    int idx = blockIdx.x * 256 + t;
    if (idx < NN) {
        rowptr[idx] += pre[idx >> 10];
        dinv[idx] = rsqrtf((float)deg[idx] + 1.0f);
    }
    if (blockIdx.x == 0 && t == 0) rowptr[NN] = pre[NB];
}

// ---------------- CSR fill, atomic-free (uses epos from gemm_deg) ----------------
__global__ void fill_csr(const int* __restrict__ src, const int* __restrict__ dst,
                         const int* __restrict__ rowptr, const int* __restrict__ epos,
                         int* __restrict__ csr_src) {
    int e = blockIdx.x * blockDim.x + threadIdx.x;
    if (e >= EE) return;
    int d = dst[e];
    csr_src[rowptr[d] + epos[e]] = src[e];
}

// ---------------- fused gather (fp16 rows, per-src dinv fma) + relu + 2-col projection -------
__global__ __launch_bounds__(256) void gather_project(const _Float16* __restrict__ hs,
                                                      const int* __restrict__ rowptr,
                                                      const int* __restrict__ csr_src,
                                                      const float* __restrict__ dinv,
                                                      const float* __restrict__ b1,
                                                      const float* __restrict__ Wft,
                                                      float2* __restrict__ q) {
    int i = blockIdx.x * 4 + (threadIdx.x >> 6);
    int l = threadIdx.x & 63;
    int lf = l & 31, le = l >> 5;
    if (i >= NN) return;
    int start = rowptr[i], end = rowptr[i + 1];
    float acc[8] = {};
    int j = start;
    for (; j + 7 < end; j += 8) {
        int s0 = csr_src[j + 0 + le];
        int s1 = csr_src[j + 2 + le];
        int s2 = csr_src[j + 4 + le];
        int s3 = csr_src[j + 6 + le];
        float d0 = dinv[s0], d1 = dinv[s1], d2 = dinv[s2], d3 = dinv[s3];
        half8v v0 = *(const half8v*)(hs + (size_t)s0 * 256 + lf * 8);
        half8v v1 = *(const half8v*)(hs + (size_t)s1 * 256 + lf * 8);
        half8v v2 = *(const half8v*)(hs + (size_t)s2 * 256 + lf * 8);
        half8v v3 = *(const half8v*)(hs + (size_t)s3 * 256 + lf * 8);
#pragma unroll
        for (int u = 0; u < 8; ++u)
            acc[u] += (d0 * (float)v0[u] + d1 * (float)v1[u]) +
                      (d2 * (float)v2[u] + d3 * (float)v3[u]);
    }
    for (; j + le < end; j += 2) {
        int s = csr_src[j + le];
        float ds = dinv[s];
        half8v v = *(const half8v*)(hs + (size_t)s * 256 + lf * 8);
#pragma unroll
        for (int u = 0; u < 8; ++u) acc[u] += ds * (float)v[u];
    }
#pragma unroll
    for (int u = 0; u < 8; ++u) acc[u] += __shfl_xor(acc[u], 32, 64);
    float di = dinv[i];
    half8v sv = *(const half8v*)(hs + (size_t)i * 256 + lf * 8);
    float q0 = 0.f, q1 = 0.f;
#pragma unroll
    for (int u = 0; u < 8; ++u) {
        float o = fmaxf((acc[u] + di * (float)sv[u]) * di + b1[lf * 8 + u], 0.f);
        q0 += o * Wft[lf * 8 + u];
        q1 += o * Wft[256 + lf * 8 + u];
    }
#pragma unroll
    for (int off = 16; off > 0; off >>= 1) {
        q0 += __shfl_xor(q0, off, 64);
        q1 += __shfl_xor(q1, off, 64);
    }
    if (l == 0) q[i] = make_float2(q0 * di, q1 * di);
}

// ---------------- gn[i] = (sum_j q[j] + q[i]) * dinv[i] ----------------
__global__ __launch_bounds__(256) void gather_gn(const float2* __restrict__ q,
                                                 const int* __restrict__ rowptr,
                                                 const int* __restrict__ csr_src,
                                                 const float* __restrict__ dinv,
                                                 float2* __restrict__ gn) {
    int i = blockIdx.x * blockDim.x + threadIdx.x;
    if (i >= NN) return;
    int start = rowptr[i], end = rowptr[i + 1];
    float a0 = 0.f, a1 = 0.f;
    for (int j = start; j < end; ++j) {
        float2 v = q[csr_src[j]];
        a0 += v.x;
        a1 += v.y;
    }
    float2 self = q[i];
    float di = dinv[i];
    gn[i] = make_float2((a0 + self.x) * di, (a1 + self.y) * di);
}

// ---------------- final edge kernel ----------------
__global__ __launch_bounds__(256) void edge_out(const float2* __restrict__ gn,
                                                const int* __restrict__ src,
                                                const int* __restrict__ dst,
                                                const int2* __restrict__ ecat,
                                                const float2* __restrict__ ev,
                                                const float* __restrict__ fW1,
                                                const float2* __restrict__ t0,
                                                const float2* __restrict__ t1,
                                                const float* __restrict__ fb1,
                                                const float* __restrict__ fW2,
                                                const float* __restrict__ fb2,
                                                float2* __restrict__ out) {
    int e = blockIdx.x * blockDim.x + threadIdx.x;
    if (e >= EE) return;
    int s = src[e], d = dst[e];
    float2 gs = gn[s], gd = gn[d];
    int2 c = ecat[e];
    float2 v = ev[e];
    float2 e0 = t0[c.x], e1 = t1[c.y];
    float z0 = gs.x - gd.x + v.x * fW1[128 * 2 + 0] + v.y * fW1[129 * 2 + 0] + e0.x + e1.x;
    float z1 = gs.y - gd.y + v.x * fW1[128 * 2 + 1] + v.y * fW1[129 * 2 + 1] + e0.y + e1.y;
    float y0 = fmaxf(z0 + fb1[0], 0.f);
    float y1 = fmaxf(z1 + fb1[1], 0.f);
    out[e] = make_float2(y0 * fW2[0] + y1 * fW2[2] + fb2[0],
                         y0 * fW2[1] + y1 * fW2[3] + fb2[1]);
}

extern "C" void kernel_launch(void* const* d_in, const int* in_sizes, int n_in,
                              void* d_out, int out_size, void* d_ws, size_t ws_size,
                              hipStream_t stream) {
    const float* x    = (const float*)d_in[0];
    const int*   eidx = (const int*)d_in[1];
    const int*   src  = eidx;
    const int*   dst  = eidx + EE;
    const int*   ecat = (const int*)d_in[2];
    const float* ev   = (const float*)d_in[3];
    const float* W1   = (const float*)d_in[4];
    const float* b1   = (const float*)d_in[5];
    const float* W2   = (const float*)d_in[6];
    // b2 (d_in[7]) cancels in gn[s]-gn[d]; unused.
    const float* emb0 = (const float*)d_in[8];
    const float* emb1 = (const float*)d_in[9];
    const float* fW1  = (const float*)d_in[10];
    const float* fb1  = (const float*)d_in[11];
    const float* fW2  = (const float*)d_in[12];
    const float* fb2  = (const float*)d_in[13];
    float* out = (float*)d_out;

    char* ws = (char*)d_ws;
    size_t off = 0;
    auto alloc = [&](size_t bytes) {
        void* p = ws + off;
        off = (off + bytes + 255) & ~(size_t)255;
        return p;
    };
    int*      deg     = (int*)alloc((size_t)NN * 4);
    float*    dinv    = (float*)alloc((size_t)NN * 4);
    int*      rowptr  = (int*)alloc((size_t)(NN + 1) * 4);
    int*      bsum    = (int*)alloc((size_t)NB * 4);
    int*      epos    = (int*)alloc((size_t)EE * 4);
    int*      csr_src = (int*)alloc((size_t)EE * 4);
    _Float16* W1T     = (_Float16*)alloc((size_t)256 * 256 * 2);
    _Float16* h1s     = (_Float16*)alloc((size_t)NN * 256 * 2);   // 25.6 MB fp16
    float2*   q       = (float2*)alloc((size_t)NN * 8);
    float2*   gn      = (float2*)alloc((size_t)NN * 8);
    float*    Wft     = (float*)alloc(512 * 4);
    float2*   t0      = (float2*)alloc(20 * 8);
    float2*   t1      = (float2*)alloc(20 * 8);

    hipMemsetAsync(deg, 0, (size_t)NN * 4, stream);

    // W1 transpose + tiny projections
    prep<<<17, 256, 0, stream>>>(W1, W2, fW1, emb0, emb1, W1T, Wft, t0, t1);

    // GEMM (graph-independent) fused with deg_count/epos
    gemm_deg<<<GEMMB + DEGB, 256, 0, stream>>>(x, W1T, h1s, NN, dst, deg, epos);

    // scan -> rowptr (+dinv)
    scan_partial<<<NB, 1024, 0, stream>>>(deg, rowptr, bsum);
    scan_add_dinv<<<(NN + 255) / 256, 256, 0, stream>>>(rowptr, bsum, deg, dinv);

    // CSR fill (atomic-free)
    fill_csr<<<DEGB, 256, 0, stream>>>(src, dst, rowptr, epos, csr_src);

    // fused gather + relu + project -> q [N,2]
    gather_project<<<(NN + 3) / 4, 256, 0, stream>>>(
        h1s, rowptr, csr_src, dinv, b1, Wft, q);
    // gn
    gather_gn<<<(NN + 255) / 256, 256, 0, stream>>>(q, rowptr, csr_src, dinv, gn);
    // edges
    edge_out<<<DEGB, 256, 0, stream>>>(
        gn, src, dst, (const int2*)ecat, (const float2*)ev,
        fW1, t0, t1, fb1, fW2, fb2, (float2*)out);
}